// Round 11
// baseline (551.855 us; speedup 1.0000x reference)
//
#include <hip/hip_runtime.h>
#include <math.h>

#define NS 200
#define FEAT 64
#define GRIDN 128

__device__ __forceinline__ float rl(float v, int l) {
    return __uint_as_float(
        __builtin_amdgcn_readlane(__float_as_uint(v), (unsigned)l));
}

// Unconditional-safe: corner indices clamped to [0,127]; out-of-range coords
// give valid=false -> contribution 0 (exact reference semantics).
__device__ __forceinline__ float trilinear(const float* __restrict__ g,
                                           float x, float y, float z) {
    const float W = 128.f, H = 128.f, D = 128.f;
    float gx = ((x + 1.f) * W - 1.f) * 0.5f;
    float gy = ((y + 1.f) * H - 1.f) * 0.5f;
    float gz = ((z + 1.f) * D - 1.f) * 0.5f;
    float x0 = floorf(gx), y0 = floorf(gy), z0 = floorf(gz);
    float out = 0.f;
#pragma unroll
    for (int dz = 0; dz < 2; ++dz)
#pragma unroll
        for (int dy = 0; dy < 2; ++dy)
#pragma unroll
            for (int dx = 0; dx < 2; ++dx) {
                float xi = x0 + dx, yi = y0 + dy, zi = z0 + dz;
                float w = (1.f - fabsf(gx - xi)) * (1.f - fabsf(gy - yi)) *
                          (1.f - fabsf(gz - zi));
                bool valid = (xi >= 0.f) && (xi < W) && (yi >= 0.f) &&
                             (yi < H) && (zi >= 0.f) && (zi < D);
                int xc = (int)fminf(fmaxf(xi, 0.f), 127.f);
                int yc = (int)fminf(fmaxf(yi, 0.f), 127.f);
                int zc = (int)fminf(fmaxf(zi, 0.f), 127.f);
                float v = valid ? g[(zc * GRIDN + yc) * GRIDN + xc] : 0.f;
                out += w * v;
            }
    return out;
}

// ws layout: ws[0..63] = w2s = fw2@sw ; ws[64] = fb2@sw + sb ;
// ((int*)ws)[66] = ray queue counter (zeroed here each launch).
__global__ __launch_bounds__(128) void precomp(const float* __restrict__ fw2,
                                               const float* __restrict__ sw,
                                               const float* __restrict__ fb2,
                                               const float* __restrict__ sb,
                                               float* __restrict__ ws) {
    int tid = threadIdx.x;
    if (tid < FEAT) {
        float a = 0.f;
        for (int j = 0; j < FEAT; ++j) a += fw2[tid * FEAT + j] * sw[j];
        ws[tid] = a;
    } else if (tid == FEAT) {
        float a = sb[0];
        for (int j = 0; j < FEAT; ++j) a += fb2[j] * sw[j];
        ws[FEAT] = a;
    } else if (tid == FEAT + 1) {
        ((int*)ws)[66] = 0;
    }
}

// One WAVE per ray, pulled from an atomic queue. No __syncthreads anywhere:
// all LDS state is per-wave, all readlane contexts are full-exec (every
// enclosing branch is wave-uniform at runtime -- round-6 lesson).
__global__ __launch_bounds__(256) void render(
    const float* __restrict__ ro, const float* __restrict__ rd,
    const float* __restrict__ gvol, const float* __restrict__ aabb,
    const float* __restrict__ fw1, const float* __restrict__ fb1,
    const float* __restrict__ fw2, const float* __restrict__ fb2,
    const float* __restrict__ rw1, const float* __restrict__ rb1,
    const float* __restrict__ rw2, const float* __restrict__ rb2,
    float* __restrict__ ws, float* __restrict__ out, int n_rays) {
    __shared__ int s_li[4][NS];    // per-wave active-sample indices
    __shared__ float s_wv[4][NS];  // per-wave active-sample weights

    const int lane = threadIdx.x & 63;
    const int wv = threadIdx.x >> 6;
    int* qctr = (int*)ws + 66;

    // ray-independent per-lane (lane = feature) constants
    const float a0x = aabb[0], a0y = aabb[1], a0z = aabb[2];
    const float a1x = aabb[3], a1y = aabb[4], a1z = aabb[5];
    const float ex = a1x - a0x, ey = a1y - a0y, ez = a1z - a0z;
    const float step = sqrtf(ex * ex + ey * ey + ez * ez) / (float)NS;
    const float i2x = 2.f / ex, i2y = 2.f / ey, i2z = 2.f / ez;
    const float wa = fw1[lane], wb = fw1[64 + lane], wc = fw1[128 + lane];
    const float wd = fb1[lane];
    const float we = ws[lane];
    const float cbias = ws[FEAT];
    const float fb2f = fb2[lane];
    const float w20 = rw2[lane * 3 + 0], w21 = rw2[lane * 3 + 1],
                w22 = rw2[lane * 3 + 2];
    const float r20 = rb2[0], r21 = rb2[1], r22 = rb2[2];
    const float rw1d0 = rw1[64 * FEAT + lane], rw1d1 = rw1[65 * FEAT + lane],
                rw1d2 = rw1[66 * FEAT + lane], rb1f = rb1[lane];

    for (;;) {
        int r0 = 0;
        if (lane == 0) r0 = atomicAdd(qctr, 1);
        const int ray = __shfl(r0, 0);
        if (ray >= n_rays) return;  // wave-uniform

        // ---- phase A: ray geometry + slab rejection ----
        const float ox = ro[ray * 3 + 0], oy = ro[ray * 3 + 1],
                    oz = ro[ray * 3 + 2];
        const float dx = rd[ray * 3 + 0], dy = rd[ray * 3 + 1],
                    dz = rd[ray * 3 + 2];
        const float ddx = (dx == 0.f) ? dx + 1e-9f : dx;
        const float ddy = (dy == 0.f) ? dy + 1e-9f : dy;
        const float ddz = (dz == 0.f) ? dz + 1e-9f : dz;
        const float r1x = (a0x - ox) / ddx, r2x = (a1x - ox) / ddx;
        const float r1y = (a0y - oy) / ddy, r2y = (a1y - oy) / ddy;
        const float r1z = (a0z - oz) / ddz, r2z = (a1z - oz) / ddz;
        const float t_lo =
            fmaxf(fmaxf(fminf(r1x, r2x), fminf(r1y, r2y)), fminf(r1z, r2z));
        const float t_hi =
            fminf(fminf(fmaxf(r1x, r2x), fmaxf(r1y, r2y)), fmaxf(r1z, r2z));
        float t_min = fminf(fmaxf(t_lo, 0.f), 100000.f);
        if (t_min > t_hi + step || t_min + 199.f * step < t_lo - step) {
            if (lane < 3) out[ray * 3 + lane] = 0.f;
            continue;  // wave-uniform
        }

        // h_j(t) = A_j + t*B_j (per-lane feature slice), computed
        // unconditionally by all 64 lanes -> readlane-safe everywhere below.
        const float cx = (ox - a0x) * i2x - 1.f;
        const float cy = (oy - a0y) * i2y - 1.f;
        const float cz = (oz - a0z) * i2z - 1.f;
        const float gx = dx * i2x, gy = dy * i2y, gz = dz * i2z;
        const float Af = cx * wa + cy * wb + cz * wc + wd;
        const float Bf = gx * wa + gy * wb + gz * wc;

        int s_begin = (int)floorf((t_lo - t_min) / step) - 1;
        if (s_begin < 0) s_begin = 0;
        int s_end = (int)ceilf((t_hi - t_min) / step) + 1;
        if (s_end > NS - 1) s_end = NS - 1;

        // ---- phase B+C: lane = sample; per-chunk scan + ballot compaction --
        float carry = 0.f;
        int cnt = 0;
#pragma unroll
        for (int c = 0; c < 4; ++c) {
            const int s = c * 64 + lane;
            float sig = 0.f;
            if (c * 64 + 63 >= s_begin && c * 64 <= s_end) {  // wave-uniform
                const float t = t_min + (float)s * step;
                const float px = ox + dx * t, py = oy + dy * t,
                            pz = oz + dz * t;
                const bool inside = (px >= a0x) & (px <= a1x) & (py >= a0y) &
                                    (py <= a1y) & (pz >= a0z) & (pz <= a1z);
                const float occ =
                    trilinear(gvol, (px - a0x) / ex * 2.f - 1.f,
                              (py - a0y) / ey * 2.f - 1.f,
                              (pz - a0z) / ez * 2.f - 1.f);
                const bool m = inside && (occ > 0.01f);
                // unconditional full-exec dot: readlane of Af/Bf/we is safe
                float q0 = 0.f, q1 = 0.f;
#pragma unroll 4
                for (int j = 0; j < FEAT; j += 2) {
                    q0 += fmaxf(rl(Af, j) + t * rl(Bf, j), 0.f) * rl(we, j);
                    q1 += fmaxf(rl(Af, j + 1) + t * rl(Bf, j + 1), 0.f) *
                          rl(we, j + 1);
                }
                sig = m ? (cbias + q0 + q1) : 0.f;
            }
            // chunk scan (Hillis-Steele over 64 lanes) + running carry
            const float la = -sig * step;
            float run = la;
#pragma unroll
            for (int off = 1; off < 64; off <<= 1) {
                float v = __shfl_up(run, off);
                if (lane >= off) run += v;
            }
            const float trans = expf(carry + run - la);  // exclusive prefix
            const float w = (trans > 1e-4f) ? trans * (1.f - expf(la)) : 0.f;
            carry += __shfl(run, 63);
            // ballot compaction (order-preserving, no atomics)
            const unsigned long long mk = __ballot(w != 0.f);
            const int pos =
                cnt + (int)__popcll(mk & ((1ull << lane) - 1ull));
            if (w != 0.f) {
                s_li[wv][pos] = s;
                s_wv[wv][pos] = w;
            }
            cnt += (int)__popcll(mk);
        }
        if (cnt == 0) {
            if (lane < 3) out[ray * 3 + lane] = 0.f;
            continue;  // wave-uniform
        }

        // ---- phase E: rgb head, 2 samples/iter, shared weight loads ----
        const float rh_dir = dx * rw1d0 + dy * rw1d1 + dz * rw1d2 + rb1f;
        float a0 = 0.f, a1 = 0.f, a2 = 0.f;
        for (int i0 = 0; i0 < cnt; i0 += 2) {
            const bool hasB = (i0 + 1) < cnt;  // wave-uniform
            const int sA = s_li[wv][i0];
            const int sB = s_li[wv][hasB ? i0 + 1 : i0];
            const float wA = s_wv[wv][i0];
            const float wB = hasB ? s_wv[wv][i0 + 1] : 0.f;
            const float tA = t_min + (float)sA * step;
            const float tB = t_min + (float)sB * step;
            const float hA = fmaxf(Af + tA * Bf, 0.f);
            const float hB = fmaxf(Af + tB * Bf, 0.f);
            float eA0 = 0.f, eA1 = 0.f, eB0 = 0.f, eB1 = 0.f;
#pragma unroll 4
            for (int j = 0; j < FEAT; j += 2) {
                const float u0 = fw2[j * FEAT + lane];
                const float u1 = fw2[(j + 1) * FEAT + lane];
                eA0 += rl(hA, j) * u0;
                eB0 += rl(hB, j) * u0;
                eA1 += rl(hA, j + 1) * u1;
                eB1 += rl(hB, j + 1) * u1;
            }
            const float feA = fb2f + (eA0 + eA1);
            const float feB = fb2f + (eB0 + eB1);
            float gA0 = 0.f, gA1 = 0.f, gB0 = 0.f, gB1 = 0.f;
#pragma unroll 4
            for (int j = 0; j < FEAT; j += 2) {
                const float u0 = rw1[j * FEAT + lane];
                const float u1 = rw1[(j + 1) * FEAT + lane];
                gA0 += rl(feA, j) * u0;
                gB0 += rl(feB, j) * u0;
                gA1 += rl(feA, j + 1) * u1;
                gB1 += rl(feB, j + 1) * u1;
            }
            const float rhA = fmaxf(rh_dir + (gA0 + gA1), 0.f);
            const float rhB = fmaxf(rh_dir + (gB0 + gB1), 0.f);
            float qA0 = rhA * w20, qA1 = rhA * w21, qA2 = rhA * w22;
            float qB0 = rhB * w20, qB1 = rhB * w21, qB2 = rhB * w22;
#pragma unroll
            for (int off = 32; off > 0; off >>= 1) {
                qA0 += __shfl_xor(qA0, off);
                qA1 += __shfl_xor(qA1, off);
                qA2 += __shfl_xor(qA2, off);
                qB0 += __shfl_xor(qB0, off);
                qB1 += __shfl_xor(qB1, off);
                qB2 += __shfl_xor(qB2, off);
            }
            a0 += wA / (1.f + expf(-(qA0 + r20))) +
                  wB / (1.f + expf(-(qB0 + r20)));
            a1 += wA / (1.f + expf(-(qA1 + r21))) +
                  wB / (1.f + expf(-(qB1 + r21)));
            a2 += wA / (1.f + expf(-(qA2 + r22))) +
                  wB / (1.f + expf(-(qB2 + r22)));
        }
        if (lane == 0) {
            out[ray * 3 + 0] = a0;
            out[ray * 3 + 1] = a1;
            out[ray * 3 + 2] = a2;
        }
    }
}

extern "C" void kernel_launch(void* const* d_in, const int* in_sizes, int n_in,
                              void* d_out, int out_size, void* d_ws,
                              size_t ws_size, hipStream_t stream) {
    const float* rays_o = (const float*)d_in[0];
    const float* rays_d = (const float*)d_in[1];
    const float* grid = (const float*)d_in[2];
    const float* aabb = (const float*)d_in[3];
    const float* fw1 = (const float*)d_in[4];
    const float* fb1 = (const float*)d_in[5];
    const float* fw2 = (const float*)d_in[6];
    const float* fb2 = (const float*)d_in[7];
    const float* sw = (const float*)d_in[8];
    const float* sb = (const float*)d_in[9];
    const float* rw1 = (const float*)d_in[10];
    const float* rb1 = (const float*)d_in[11];
    const float* rw2 = (const float*)d_in[12];
    const float* rb2 = (const float*)d_in[13];
    float* out = (float*)d_out;
    float* ws = (float*)d_ws;
    const int n_rays = in_sizes[0] / 3;

    precomp<<<1, 128, 0, stream>>>(fw2, sw, fb2, sb, ws);
    render<<<2048, 256, 0, stream>>>(rays_o, rays_d, grid, aabb, fw1, fb1,
                                     fw2, fb2, rw1, rb1, rw2, rb2, ws, out,
                                     n_rays);
}

// Round 12
// 166.158 us; speedup vs baseline: 3.3213x; 3.3213x over previous
//
#include <hip/hip_runtime.h>
#include <math.h>

#define NS 200
#define FEAT 64
#define GRIDN 128

__device__ __forceinline__ float rl(float v, int l) {
    return __uint_as_float(
        __builtin_amdgcn_readlane(__float_as_uint(v), (unsigned)l));
}

// Corner indices clamped to [0,127]; out-of-range coords give valid=false ->
// contribution 0 (exact reference semantics).
__device__ __forceinline__ float trilinear(const float* __restrict__ g,
                                           float x, float y, float z) {
    const float W = 128.f, H = 128.f, D = 128.f;
    float gx = ((x + 1.f) * W - 1.f) * 0.5f;
    float gy = ((y + 1.f) * H - 1.f) * 0.5f;
    float gz = ((z + 1.f) * D - 1.f) * 0.5f;
    float x0 = floorf(gx), y0 = floorf(gy), z0 = floorf(gz);
    float out = 0.f;
#pragma unroll
    for (int dz = 0; dz < 2; ++dz)
#pragma unroll
        for (int dy = 0; dy < 2; ++dy)
#pragma unroll
            for (int dx = 0; dx < 2; ++dx) {
                float xi = x0 + dx, yi = y0 + dy, zi = z0 + dz;
                float w = (1.f - fabsf(gx - xi)) * (1.f - fabsf(gy - yi)) *
                          (1.f - fabsf(gz - zi));
                bool valid = (xi >= 0.f) && (xi < W) && (yi >= 0.f) &&
                             (yi < H) && (zi >= 0.f) && (zi < D);
                int xc = (int)fminf(fmaxf(xi, 0.f), 127.f);
                int yc = (int)fminf(fmaxf(yi, 0.f), 127.f);
                int zc = (int)fminf(fmaxf(zi, 0.f), 127.f);
                float v = valid ? g[(zc * GRIDN + yc) * GRIDN + xc] : 0.f;
                out += w * v;
            }
    return out;
}

// ws usage: ONLY 65 floats. ws[0..63] = w2s = fw2@sw ; ws[64] = fb2@sw + sb
__global__ __launch_bounds__(128) void precomp(const float* __restrict__ fw2,
                                               const float* __restrict__ sw,
                                               const float* __restrict__ fb2,
                                               const float* __restrict__ sb,
                                               float* __restrict__ ws) {
    int tid = threadIdx.x;
    if (tid < FEAT) {
        float a = 0.f;
        for (int j = 0; j < FEAT; ++j) a += fw2[tid * FEAT + j] * sw[j];
        ws[tid] = a;
    } else if (tid == FEAT) {
        float a = sb[0];
        for (int j = 0; j < FEAT; ++j) a += fb2[j] * sw[j];
        ws[FEAT] = a;
    }
}

// Block = ray (grid-launched). Phase B is thread=sample (200-way parallel,
// round-3-proven locality: FETCH ~9MB). Plain __launch_bounds__(256): the
// (256,8) variant caused VGPR-32 spills (rounds 7/8, 105MB WRITE_SIZE).
__global__ __launch_bounds__(256) void render(
    const float* __restrict__ ro, const float* __restrict__ rd,
    const float* __restrict__ gvol, const float* __restrict__ aabb,
    const float* __restrict__ fw1, const float* __restrict__ fb1,
    const float* __restrict__ fw2, const float* __restrict__ fb2,
    const float* __restrict__ rw1, const float* __restrict__ rb1,
    const float* __restrict__ rw2, const float* __restrict__ rb2,
    const float* __restrict__ ws, float* __restrict__ out) {
    __shared__ float s_Af[FEAT];  // h_j(t) = Af_j + t*Bf_j
    __shared__ float s_Bf[FEAT];
    __shared__ float s_we[FEAT];  // folded fw2@sw
    __shared__ float s_w[NS];     // effective per-sample weights
    __shared__ int s_list[NS];    // active sample indices
    __shared__ float s_wsum[4];   // per-wave scan totals
    __shared__ float s_acc[4][3];
    __shared__ int s_cnt;

    const int ray = blockIdx.x;
    const int tid = threadIdx.x;
    const int f = tid & 63, wv = tid >> 6;
    if (tid == 0) s_cnt = 0;

    // ---- phase A: ray geometry + slab rejection (block-uniform) ----
    const float ox = ro[ray * 3 + 0], oy = ro[ray * 3 + 1],
                oz = ro[ray * 3 + 2];
    const float dx = rd[ray * 3 + 0], dy = rd[ray * 3 + 1],
                dz = rd[ray * 3 + 2];
    const float a0x = aabb[0], a0y = aabb[1], a0z = aabb[2];
    const float a1x = aabb[3], a1y = aabb[4], a1z = aabb[5];
    const float ex = a1x - a0x, ey = a1y - a0y, ez = a1z - a0z;
    const float step = sqrtf(ex * ex + ey * ey + ez * ez) / (float)NS;
    const float ddx = (dx == 0.f) ? dx + 1e-9f : dx;
    const float ddy = (dy == 0.f) ? dy + 1e-9f : dy;
    const float ddz = (dz == 0.f) ? dz + 1e-9f : dz;
    const float r1x = (a0x - ox) / ddx, r2x = (a1x - ox) / ddx;
    const float r1y = (a0y - oy) / ddy, r2y = (a1y - oy) / ddy;
    const float r1z = (a0z - oz) / ddz, r2z = (a1z - oz) / ddz;
    const float t_lo =
        fmaxf(fmaxf(fminf(r1x, r2x), fminf(r1y, r2y)), fminf(r1z, r2z));
    const float t_hi =
        fminf(fminf(fmaxf(r1x, r2x), fmaxf(r1y, r2y)), fmaxf(r1z, r2z));
    float t_min = fminf(fmaxf(t_lo, 0.f), 100000.f);
    if (t_min > t_hi + step || t_min + 199.f * step < t_lo - step) {
        if (tid < 3) out[ray * 3 + tid] = 0.f;
        return;
    }

    // per-lane feature slice (lane = feature), computed by ALL threads
    const float wa = fw1[f], wb = fw1[64 + f], wc = fw1[128 + f];
    const float wd = fb1[f];
    const float we = ws[f];
    const float cbias = ws[FEAT];
    const float i2x = 2.f / ex, i2y = 2.f / ey, i2z = 2.f / ez;
    const float cx = (ox - a0x) * i2x - 1.f;
    const float cy = (oy - a0y) * i2y - 1.f;
    const float cz = (oz - a0z) * i2z - 1.f;
    const float gx = dx * i2x, gy = dy * i2y, gz = dz * i2z;
    const float Af = cx * wa + cy * wb + cz * wc + wd;
    const float Bf = gx * wa + gy * wb + gz * wc;
    // Unconditional LDS publish (round-7 fix): cross-thread consumers read
    // LDS, never possibly-inactive lanes' registers.
    if (tid < FEAT) {
        s_Af[tid] = Af;
        s_Bf[tid] = Bf;
        s_we[tid] = we;
    }

    // sample range that can possibly be inside (±1 step margin)
    int s_begin = (int)floorf((t_lo - t_min) / step) - 1;
    if (s_begin < 0) s_begin = 0;
    int s_end = (int)ceilf((t_hi - t_min) / step) + 1;
    if (s_end > NS - 1) s_end = NS - 1;

    __syncthreads();

    // ---- phase B: thread = sample, fully parallel, sigma in register ----
    float sig = 0.f;
    if (tid >= s_begin && tid <= s_end) {  // tid<NS implied (s_end<=199)
        const float t = t_min + (float)tid * step;
        const float px = ox + dx * t, py = oy + dy * t, pz = oz + dz * t;
        const bool inside = (px >= a0x) & (px <= a1x) & (py >= a0y) &
                            (py <= a1y) & (pz >= a0z) & (pz <= a1z);
        if (inside) {
            const float occ = trilinear(gvol, (px - a0x) / ex * 2.f - 1.f,
                                        (py - a0y) / ey * 2.f - 1.f,
                                        (pz - a0z) / ez * 2.f - 1.f);
            if (occ > 0.01f) {
                float q0 = 0.f, q1 = 0.f;
#pragma unroll 4
                for (int j = 0; j < FEAT; j += 2) {
                    q0 += fmaxf(s_Af[j] + t * s_Bf[j], 0.f) * s_we[j];
                    q1 += fmaxf(s_Af[j + 1] + t * s_Bf[j + 1], 0.f) *
                          s_we[j + 1];
                }
                sig = cbias + q0 + q1;
            }
        }
    }

    // ---- phase C: block scan of log_a -> weights + compaction ----
    const float la = (tid < NS) ? -sig * step : 0.f;
    float run = la;
#pragma unroll
    for (int off = 1; off < 64; off <<= 1) {
        float v = __shfl_up(run, off);
        if (f >= off) run += v;
    }
    if (f == 63) s_wsum[wv] = run;
    __syncthreads();
    float offs = 0.f;
    for (int k = 0; k < wv; ++k) offs += s_wsum[k];
    run += offs;
    if (tid < NS) {
        const float trans = expf(run - la);  // exclusive prefix
        const float w = (trans > 1e-4f) ? trans * (1.f - expf(la)) : 0.f;
        s_w[tid] = w;
        if (w != 0.f) {
            int p = atomicAdd(&s_cnt, 1);
            s_list[p] = tid;
        }
    }
    __syncthreads();
    const int cnt = s_cnt;
    if (cnt == 0) {
        if (tid < 3) out[ray * 3 + tid] = 0.f;
        return;
    }

    // ---- phase E: pairwise rgb head over compacted samples (round 9) ----
    const float fb2f = fb2[f];
    const float rh_dir = dx * rw1[64 * FEAT + f] + dy * rw1[65 * FEAT + f] +
                         dz * rw1[66 * FEAT + f] + rb1[f];
    const float w20 = rw2[f * 3 + 0], w21 = rw2[f * 3 + 1],
                w22 = rw2[f * 3 + 2];
    const float r20 = rb2[0], r21 = rb2[1], r22 = rb2[2];

    float a0 = 0.f, a1 = 0.f, a2 = 0.f;
    for (int i0 = 2 * wv; i0 < cnt; i0 += 8) {
        const bool hasB = (i0 + 1) < cnt;  // wave-uniform
        const int sA = s_list[i0];
        const int sB = s_list[hasB ? i0 + 1 : i0];
        const float wA = s_w[sA];
        const float wB = hasB ? s_w[sB] : 0.f;
        const float tA = t_min + (float)sA * step;
        const float tB = t_min + (float)sB * step;
        // all 64 lanes compute h (wave-uniform region) -> readlane safe
        const float hA = fmaxf(Af + tA * Bf, 0.f);
        const float hB = fmaxf(Af + tB * Bf, 0.f);
        float eA0 = 0.f, eA1 = 0.f, eB0 = 0.f, eB1 = 0.f;
#pragma unroll 4
        for (int j = 0; j < FEAT; j += 2) {
            const float u0 = fw2[j * FEAT + f];
            const float u1 = fw2[(j + 1) * FEAT + f];
            eA0 += rl(hA, j) * u0;
            eB0 += rl(hB, j) * u0;
            eA1 += rl(hA, j + 1) * u1;
            eB1 += rl(hB, j + 1) * u1;
        }
        const float feA = fb2f + (eA0 + eA1);
        const float feB = fb2f + (eB0 + eB1);
        float gA0 = 0.f, gA1 = 0.f, gB0 = 0.f, gB1 = 0.f;
#pragma unroll 4
        for (int j = 0; j < FEAT; j += 2) {
            const float u0 = rw1[j * FEAT + f];
            const float u1 = rw1[(j + 1) * FEAT + f];
            gA0 += rl(feA, j) * u0;
            gB0 += rl(feB, j) * u0;
            gA1 += rl(feA, j + 1) * u1;
            gB1 += rl(feB, j + 1) * u1;
        }
        const float rhA = fmaxf(rh_dir + (gA0 + gA1), 0.f);
        const float rhB = fmaxf(rh_dir + (gB0 + gB1), 0.f);
        float qA0 = rhA * w20, qA1 = rhA * w21, qA2 = rhA * w22;
        float qB0 = rhB * w20, qB1 = rhB * w21, qB2 = rhB * w22;
#pragma unroll
        for (int off = 32; off > 0; off >>= 1) {
            qA0 += __shfl_xor(qA0, off);
            qA1 += __shfl_xor(qA1, off);
            qA2 += __shfl_xor(qA2, off);
            qB0 += __shfl_xor(qB0, off);
            qB1 += __shfl_xor(qB1, off);
            qB2 += __shfl_xor(qB2, off);
        }
        a0 += wA / (1.f + expf(-(qA0 + r20))) +
              wB / (1.f + expf(-(qB0 + r20)));
        a1 += wA / (1.f + expf(-(qA1 + r21))) +
              wB / (1.f + expf(-(qB1 + r21)));
        a2 += wA / (1.f + expf(-(qA2 + r22))) +
              wB / (1.f + expf(-(qB2 + r22)));
    }
    if (f == 0) {
        s_acc[wv][0] = a0;
        s_acc[wv][1] = a1;
        s_acc[wv][2] = a2;
    }
    __syncthreads();
    if (tid == 0) {
        out[ray * 3 + 0] =
            s_acc[0][0] + s_acc[1][0] + s_acc[2][0] + s_acc[3][0];
        out[ray * 3 + 1] =
            s_acc[0][1] + s_acc[1][1] + s_acc[2][1] + s_acc[3][1];
        out[ray * 3 + 2] =
            s_acc[0][2] + s_acc[1][2] + s_acc[2][2] + s_acc[3][2];
    }
}

extern "C" void kernel_launch(void* const* d_in, const int* in_sizes, int n_in,
                              void* d_out, int out_size, void* d_ws,
                              size_t ws_size, hipStream_t stream) {
    const float* rays_o = (const float*)d_in[0];
    const float* rays_d = (const float*)d_in[1];
    const float* grid = (const float*)d_in[2];
    const float* aabb = (const float*)d_in[3];
    const float* fw1 = (const float*)d_in[4];
    const float* fb1 = (const float*)d_in[5];
    const float* fw2 = (const float*)d_in[6];
    const float* fb2 = (const float*)d_in[7];
    const float* sw = (const float*)d_in[8];
    const float* sb = (const float*)d_in[9];
    const float* rw1 = (const float*)d_in[10];
    const float* rb1 = (const float*)d_in[11];
    const float* rw2 = (const float*)d_in[12];
    const float* rb2 = (const float*)d_in[13];
    float* out = (float*)d_out;
    float* ws = (float*)d_ws;
    const int n_rays = in_sizes[0] / 3;

    precomp<<<1, 128, 0, stream>>>(fw2, sw, fb2, sb, ws);
    render<<<n_rays, 256, 0, stream>>>(rays_o, rays_d, grid, aabb, fw1, fb1,
                                       fw2, fb2, rw1, rb1, rw2, rb2, ws, out);
}

// Round 13
// 160.136 us; speedup vs baseline: 3.4462x; 1.0376x over previous
//
#include <hip/hip_runtime.h>
#include <math.h>

#define NS 200
#define FEAT 64
#define GRIDN 128

__device__ __forceinline__ float rl(float v, int l) {
    return __uint_as_float(
        __builtin_amdgcn_readlane(__float_as_uint(v), (unsigned)l));
}

// Corner indices clamped to [0,127]; out-of-range coords give valid=false ->
// contribution 0 (exact reference semantics).
__device__ __forceinline__ float trilinear(const float* __restrict__ g,
                                           float x, float y, float z) {
    const float W = 128.f, H = 128.f, D = 128.f;
    float gx = ((x + 1.f) * W - 1.f) * 0.5f;
    float gy = ((y + 1.f) * H - 1.f) * 0.5f;
    float gz = ((z + 1.f) * D - 1.f) * 0.5f;
    float x0 = floorf(gx), y0 = floorf(gy), z0 = floorf(gz);
    float out = 0.f;
#pragma unroll
    for (int dz = 0; dz < 2; ++dz)
#pragma unroll
        for (int dy = 0; dy < 2; ++dy)
#pragma unroll
            for (int dx = 0; dx < 2; ++dx) {
                float xi = x0 + dx, yi = y0 + dy, zi = z0 + dz;
                float w = (1.f - fabsf(gx - xi)) * (1.f - fabsf(gy - yi)) *
                          (1.f - fabsf(gz - zi));
                bool valid = (xi >= 0.f) && (xi < W) && (yi >= 0.f) &&
                             (yi < H) && (zi >= 0.f) && (zi < D);
                int xc = (int)fminf(fmaxf(xi, 0.f), 127.f);
                int yc = (int)fminf(fmaxf(yi, 0.f), 127.f);
                int zc = (int)fminf(fmaxf(zi, 0.f), 127.f);
                float v = valid ? g[(zc * GRIDN + yc) * GRIDN + xc] : 0.f;
                out += w * v;
            }
    return out;
}

// ws usage: ONLY 65 floats. ws[0..63] = w2s = fw2@sw ; ws[64] = fb2@sw + sb
__global__ __launch_bounds__(128) void precomp(const float* __restrict__ fw2,
                                               const float* __restrict__ sw,
                                               const float* __restrict__ fb2,
                                               const float* __restrict__ sb,
                                               float* __restrict__ ws) {
    int tid = threadIdx.x;
    if (tid < FEAT) {
        float a = 0.f;
        for (int j = 0; j < FEAT; ++j) a += fw2[tid * FEAT + j] * sw[j];
        ws[tid] = a;
    } else if (tid == FEAT) {
        float a = sb[0];
        for (int j = 0; j < FEAT; ++j) a += fb2[j] * sw[j];
        ws[FEAT] = a;
    }
}

// Block = ray. Phase B thread=sample with readlane dot; phase E 4-sample ILP.
// Plain __launch_bounds__(256): (256,8) caused VGPR-32 spills (rounds 7/8).
__global__ __launch_bounds__(256) void render(
    const float* __restrict__ ro, const float* __restrict__ rd,
    const float* __restrict__ gvol, const float* __restrict__ aabb,
    const float* __restrict__ fw1, const float* __restrict__ fb1,
    const float* __restrict__ fw2, const float* __restrict__ fb2,
    const float* __restrict__ rw1, const float* __restrict__ rb1,
    const float* __restrict__ rw2, const float* __restrict__ rb2,
    const float* __restrict__ ws, float* __restrict__ out) {
    __shared__ float s_w[NS];    // effective per-sample weights
    __shared__ int s_list[NS];   // active sample indices
    __shared__ float s_wsum[4];  // per-wave scan totals
    __shared__ float s_acc[4][3];
    __shared__ int s_cnt;

    const int ray = blockIdx.x;
    const int tid = threadIdx.x;
    const int f = tid & 63, wv = tid >> 6;
    if (tid == 0) s_cnt = 0;

    // ---- phase A: ray geometry + slab rejection (block-uniform) ----
    const float ox = ro[ray * 3 + 0], oy = ro[ray * 3 + 1],
                oz = ro[ray * 3 + 2];
    const float dx = rd[ray * 3 + 0], dy = rd[ray * 3 + 1],
                dz = rd[ray * 3 + 2];
    const float a0x = aabb[0], a0y = aabb[1], a0z = aabb[2];
    const float a1x = aabb[3], a1y = aabb[4], a1z = aabb[5];
    const float ex = a1x - a0x, ey = a1y - a0y, ez = a1z - a0z;
    const float step = sqrtf(ex * ex + ey * ey + ez * ez) / (float)NS;
    const float ddx = (dx == 0.f) ? dx + 1e-9f : dx;
    const float ddy = (dy == 0.f) ? dy + 1e-9f : dy;
    const float ddz = (dz == 0.f) ? dz + 1e-9f : dz;
    const float r1x = (a0x - ox) / ddx, r2x = (a1x - ox) / ddx;
    const float r1y = (a0y - oy) / ddy, r2y = (a1y - oy) / ddy;
    const float r1z = (a0z - oz) / ddz, r2z = (a1z - oz) / ddz;
    const float t_lo =
        fmaxf(fmaxf(fminf(r1x, r2x), fminf(r1y, r2y)), fminf(r1z, r2z));
    const float t_hi =
        fminf(fminf(fmaxf(r1x, r2x), fmaxf(r1y, r2y)), fmaxf(r1z, r2z));
    float t_min = fminf(fmaxf(t_lo, 0.f), 100000.f);
    if (t_min > t_hi + step || t_min + 199.f * step < t_lo - step) {
        if (tid < 3) out[ray * 3 + tid] = 0.f;
        return;
    }

    // per-lane feature slice (lane = feature), computed by ALL threads with
    // full exec, then pinned live via empty volatile asm (rule #17) so the
    // compiler cannot sink the computation under a divergent exec mask
    // (round-6 bug class). readlane of these registers is then always safe.
    const float wa = fw1[f], wb = fw1[64 + f], wc = fw1[128 + f];
    const float wd = fb1[f];
    const float we = ws[f];
    const float cbias = ws[FEAT];
    const float i2x = 2.f / ex, i2y = 2.f / ey, i2z = 2.f / ez;
    const float cx = (ox - a0x) * i2x - 1.f;
    const float cy = (oy - a0y) * i2y - 1.f;
    const float cz = (oz - a0z) * i2z - 1.f;
    const float gx = dx * i2x, gy = dy * i2y, gz = dz * i2z;
    const float Af = cx * wa + cy * wb + cz * wc + wd;
    const float Bf = gx * wa + gy * wb + gz * wc;
    asm volatile("" ::"v"(Af), "v"(Bf), "v"(we));

    // sample range that can possibly be inside (±1 step margin)
    int s_begin = (int)floorf((t_lo - t_min) / step) - 1;
    if (s_begin < 0) s_begin = 0;
    int s_end = (int)ceilf((t_hi - t_min) / step) + 1;
    if (s_end > NS - 1) s_end = NS - 1;

    // ---- phase B: thread = sample; sigma via readlane dot (no LDS) ----
    float sig = 0.f;
    if (tid >= s_begin && tid <= s_end) {  // tid<NS implied (s_end<=199)
        const float t = t_min + (float)tid * step;
        const float px = ox + dx * t, py = oy + dy * t, pz = oz + dz * t;
        const bool inside = (px >= a0x) & (px <= a1x) & (py >= a0y) &
                            (py <= a1y) & (pz >= a0z) & (pz <= a1z);
        if (inside) {
            const float occ = trilinear(gvol, (px - a0x) / ex * 2.f - 1.f,
                                        (py - a0y) / ey * 2.f - 1.f,
                                        (pz - a0z) / ez * 2.f - 1.f);
            if (occ > 0.01f) {
                float q0 = 0.f, q1 = 0.f, q2 = 0.f, q3 = 0.f;
#pragma unroll 4
                for (int j = 0; j < FEAT; j += 4) {
                    q0 += fmaxf(rl(Af, j) + t * rl(Bf, j), 0.f) * rl(we, j);
                    q1 += fmaxf(rl(Af, j + 1) + t * rl(Bf, j + 1), 0.f) *
                          rl(we, j + 1);
                    q2 += fmaxf(rl(Af, j + 2) + t * rl(Bf, j + 2), 0.f) *
                          rl(we, j + 2);
                    q3 += fmaxf(rl(Af, j + 3) + t * rl(Bf, j + 3), 0.f) *
                          rl(we, j + 3);
                }
                sig = cbias + ((q0 + q1) + (q2 + q3));
            }
        }
    }

    // ---- phase C: block scan of log_a -> weights + compaction ----
    const float la = (tid < NS) ? -sig * step : 0.f;
    float run = la;
#pragma unroll
    for (int off = 1; off < 64; off <<= 1) {
        float v = __shfl_up(run, off);
        if (f >= off) run += v;
    }
    if (f == 63) s_wsum[wv] = run;
    __syncthreads();
    float offs = 0.f;
    for (int k = 0; k < wv; ++k) offs += s_wsum[k];
    run += offs;
    if (tid < NS) {
        const float trans = expf(run - la);  // exclusive prefix
        const float w = (trans > 1e-4f) ? trans * (1.f - expf(la)) : 0.f;
        s_w[tid] = w;
        if (w != 0.f) {
            int p = atomicAdd(&s_cnt, 1);
            s_list[p] = tid;
        }
    }
    __syncthreads();
    const int cnt = s_cnt;
    if (cnt == 0) {
        if (tid < 3) out[ray * 3 + tid] = 0.f;
        return;
    }

    // ---- phase E: rgb head, 4 samples/wave/iter, shared weight loads ----
    const float fb2f = fb2[f];
    const float rh_dir = dx * rw1[64 * FEAT + f] + dy * rw1[65 * FEAT + f] +
                         dz * rw1[66 * FEAT + f] + rb1[f];
    const float w20 = rw2[f * 3 + 0], w21 = rw2[f * 3 + 1],
                w22 = rw2[f * 3 + 2];
    const float r20 = rb2[0], r21 = rb2[1], r22 = rb2[2];

    float a0 = 0.f, a1 = 0.f, a2 = 0.f;
    for (int i0 = 4 * wv; i0 < cnt; i0 += 16) {
        const bool hB = (i0 + 1) < cnt;  // wave-uniform
        const bool hC = (i0 + 2) < cnt;
        const bool hD = (i0 + 3) < cnt;
        const int sA = s_list[i0];
        const int sB = s_list[hB ? i0 + 1 : i0];
        const int sC = s_list[hC ? i0 + 2 : i0];
        const int sD = s_list[hD ? i0 + 3 : i0];
        const float wA = s_w[sA];
        const float wB = hB ? s_w[sB] : 0.f;
        const float wC = hC ? s_w[sC] : 0.f;
        const float wD = hD ? s_w[sD] : 0.f;
        const float tA = t_min + (float)sA * step;
        const float tB = t_min + (float)sB * step;
        const float tC = t_min + (float)sC * step;
        const float tD = t_min + (float)sD * step;
        // h computed by ALL 64 lanes (wave-uniform region) -> readlane safe
        const float hA = fmaxf(Af + tA * Bf, 0.f);
        const float hB_ = fmaxf(Af + tB * Bf, 0.f);
        const float hC_ = fmaxf(Af + tC * Bf, 0.f);
        const float hD_ = fmaxf(Af + tD * Bf, 0.f);
        float eA0 = 0.f, eA1 = 0.f, eB0 = 0.f, eB1 = 0.f;
        float eC0 = 0.f, eC1 = 0.f, eD0 = 0.f, eD1 = 0.f;
#pragma unroll 4
        for (int j = 0; j < FEAT; j += 2) {
            const float u0 = fw2[j * FEAT + f];
            const float u1 = fw2[(j + 1) * FEAT + f];
            eA0 += rl(hA, j) * u0;
            eB0 += rl(hB_, j) * u0;
            eC0 += rl(hC_, j) * u0;
            eD0 += rl(hD_, j) * u0;
            eA1 += rl(hA, j + 1) * u1;
            eB1 += rl(hB_, j + 1) * u1;
            eC1 += rl(hC_, j + 1) * u1;
            eD1 += rl(hD_, j + 1) * u1;
        }
        const float feA = fb2f + (eA0 + eA1);
        const float feB = fb2f + (eB0 + eB1);
        const float feC = fb2f + (eC0 + eC1);
        const float feD = fb2f + (eD0 + eD1);
        float gA0 = 0.f, gA1 = 0.f, gB0 = 0.f, gB1 = 0.f;
        float gC0 = 0.f, gC1 = 0.f, gD0 = 0.f, gD1 = 0.f;
#pragma unroll 4
        for (int j = 0; j < FEAT; j += 2) {
            const float u0 = rw1[j * FEAT + f];
            const float u1 = rw1[(j + 1) * FEAT + f];
            gA0 += rl(feA, j) * u0;
            gB0 += rl(feB, j) * u0;
            gC0 += rl(feC, j) * u0;
            gD0 += rl(feD, j) * u0;
            gA1 += rl(feA, j + 1) * u1;
            gB1 += rl(feB, j + 1) * u1;
            gC1 += rl(feC, j + 1) * u1;
            gD1 += rl(feD, j + 1) * u1;
        }
        const float rhA = fmaxf(rh_dir + (gA0 + gA1), 0.f);
        const float rhB = fmaxf(rh_dir + (gB0 + gB1), 0.f);
        const float rhC = fmaxf(rh_dir + (gC0 + gC1), 0.f);
        const float rhD = fmaxf(rh_dir + (gD0 + gD1), 0.f);
        float qA0 = rhA * w20, qA1 = rhA * w21, qA2 = rhA * w22;
        float qB0 = rhB * w20, qB1 = rhB * w21, qB2 = rhB * w22;
        float qC0 = rhC * w20, qC1 = rhC * w21, qC2 = rhC * w22;
        float qD0 = rhD * w20, qD1 = rhD * w21, qD2 = rhD * w22;
#pragma unroll
        for (int off = 32; off > 0; off >>= 1) {
            qA0 += __shfl_xor(qA0, off);
            qA1 += __shfl_xor(qA1, off);
            qA2 += __shfl_xor(qA2, off);
            qB0 += __shfl_xor(qB0, off);
            qB1 += __shfl_xor(qB1, off);
            qB2 += __shfl_xor(qB2, off);
            qC0 += __shfl_xor(qC0, off);
            qC1 += __shfl_xor(qC1, off);
            qC2 += __shfl_xor(qC2, off);
            qD0 += __shfl_xor(qD0, off);
            qD1 += __shfl_xor(qD1, off);
            qD2 += __shfl_xor(qD2, off);
        }
        a0 += wA / (1.f + expf(-(qA0 + r20))) +
              wB / (1.f + expf(-(qB0 + r20))) +
              wC / (1.f + expf(-(qC0 + r20))) +
              wD / (1.f + expf(-(qD0 + r20)));
        a1 += wA / (1.f + expf(-(qA1 + r21))) +
              wB / (1.f + expf(-(qB1 + r21))) +
              wC / (1.f + expf(-(qC1 + r21))) +
              wD / (1.f + expf(-(qD1 + r21)));
        a2 += wA / (1.f + expf(-(qA2 + r22))) +
              wB / (1.f + expf(-(qB2 + r22))) +
              wC / (1.f + expf(-(qC2 + r22))) +
              wD / (1.f + expf(-(qD2 + r22)));
    }
    if (f == 0) {
        s_acc[wv][0] = a0;
        s_acc[wv][1] = a1;
        s_acc[wv][2] = a2;
    }
    __syncthreads();
    if (tid == 0) {
        out[ray * 3 + 0] =
            s_acc[0][0] + s_acc[1][0] + s_acc[2][0] + s_acc[3][0];
        out[ray * 3 + 1] =
            s_acc[0][1] + s_acc[1][1] + s_acc[2][1] + s_acc[3][1];
        out[ray * 3 + 2] =
            s_acc[0][2] + s_acc[1][2] + s_acc[2][2] + s_acc[3][2];
    }
}

extern "C" void kernel_launch(void* const* d_in, const int* in_sizes, int n_in,
                              void* d_out, int out_size, void* d_ws,
                              size_t ws_size, hipStream_t stream) {
    const float* rays_o = (const float*)d_in[0];
    const float* rays_d = (const float*)d_in[1];
    const float* grid = (const float*)d_in[2];
    const float* aabb = (const float*)d_in[3];
    const float* fw1 = (const float*)d_in[4];
    const float* fb1 = (const float*)d_in[5];
    const float* fw2 = (const float*)d_in[6];
    const float* fb2 = (const float*)d_in[7];
    const float* sw = (const float*)d_in[8];
    const float* sb = (const float*)d_in[9];
    const float* rw1 = (const float*)d_in[10];
    const float* rb1 = (const float*)d_in[11];
    const float* rw2 = (const float*)d_in[12];
    const float* rb2 = (const float*)d_in[13];
    float* out = (float*)d_out;
    float* ws = (float*)d_ws;
    const int n_rays = in_sizes[0] / 3;

    precomp<<<1, 128, 0, stream>>>(fw2, sw, fb2, sb, ws);
    render<<<n_rays, 256, 0, stream>>>(rays_o, rays_d, grid, aabb, fw1, fb1,
                                       fw2, fb2, rw1, rb1, rw2, rb2, ws, out);
}